// Round 1
// baseline (240.367 us; speedup 1.0000x reference)
//
#include <hip/hip_runtime.h>

#define NBINS 50

// Gaussian kernel (5 taps, sigma=0.5), normalized: exp(-2*x^2)/sum, x=-2..2
// K0 = e^-8/S, K1 = e^-2/S, K2 = 1/S, S = 1 + 2e^-2 + 2e^-8
#define K0 2.6387004e-4f
#define K1 1.0645079e-1f
#define K2 7.8657085e-1f

__device__ __forceinline__ float tgt_weight(int j, int q) {
  // 5-tap reflect-padded blur of one-hot(q), evaluated at bin j
  float t = 0.f;
#pragma unroll
  for (int i = 0; i < 5; ++i) {
    int m = j - 2 + i;
    m = (m < 0) ? -m : m;
    m = (m > NBINS - 1) ? (2 * (NBINS - 1) - m) : m;
    float kv = (i == 2) ? K2 : ((i == 1 || i == 3) ? K1 : K0);
    t += (m == q) ? kv : 0.f;
  }
  return t;
}

__device__ __forceinline__ int quant(int g) {
  // exact integer floor((g-50)/6) clipped to [0, 49]; g in [0,200)
  int d = g - 50;
  int q = (d < 0) ? 0 : (d / 6);
  return (q > NBINS - 1) ? (NBINS - 1) : q;
}

__global__ __launch_bounds__(256) void pitch_loss_main(
    const float* __restrict__ preds,
    const int* __restrict__ gt,
    float* __restrict__ acc,   // acc[0] = loss sum, acc[1] = valid count
    int total)
{
  float num = 0.f;
  float den = 0.f;

  const int nvec = total >> 2;
  const int stride = gridDim.x * blockDim.x;

  for (int v = blockIdx.x * blockDim.x + threadIdx.x; v < nvec; v += stride) {
    const float4 p4 = reinterpret_cast<const float4*>(preds)[v];
    const int e0 = v << 2;
    const int f0 = e0 / NBINS;          // frame of first element
    const int j0 = e0 - f0 * NBINS;     // bin of first element
    const int g0 = gt[f0];
    const int g1 = (j0 + 3 >= NBINS) ? gt[f0 + 1] : g0;  // crosses frame boundary?

    float p[4] = {p4.x, p4.y, p4.z, p4.w};
#pragma unroll
    for (int u = 0; u < 4; ++u) {
      int j = j0 + u;
      const int g = (j >= NBINS) ? g1 : g0;
      if (j >= NBINS) j -= NBINS;
      if (g != 100) {                    // not padded/unvoiced
        const int q = quant(g);
        const float t = tgt_weight(j, q);
        const float x = p[u];
        const float sp = fmaxf(x, 0.f) + __logf(1.f + __expf(-fabsf(x)));
        num += sp - x * t;
        den += 1.f;
      }
    }
  }

  // scalar tail (empty for the given sizes, kept for generality)
  for (int e = (nvec << 2) + blockIdx.x * blockDim.x + threadIdx.x; e < total;
       e += stride) {
    const int f = e / NBINS;
    const int j = e - f * NBINS;
    const int g = gt[f];
    if (g != 100) {
      const int q = quant(g);
      const float t = tgt_weight(j, q);
      const float x = preds[e];
      const float sp = fmaxf(x, 0.f) + __logf(1.f + __expf(-fabsf(x)));
      num += sp - x * t;
      den += 1.f;
    }
  }

  // wave-64 shuffle reduction
#pragma unroll
  for (int off = 32; off > 0; off >>= 1) {
    num += __shfl_down(num, off, 64);
    den += __shfl_down(den, off, 64);
  }
  __shared__ float s_num[4];
  __shared__ float s_den[4];
  const int wave = threadIdx.x >> 6;
  if ((threadIdx.x & 63) == 0) { s_num[wave] = num; s_den[wave] = den; }
  __syncthreads();
  if (threadIdx.x == 0) {
    const float n = s_num[0] + s_num[1] + s_num[2] + s_num[3];
    const float d = s_den[0] + s_den[1] + s_den[2] + s_den[3];
    atomicAdd(&acc[0], n);
    atomicAdd(&acc[1], d);
  }
}

__global__ void pitch_loss_finalize(const float* __restrict__ acc,
                                    float* __restrict__ out) {
  out[0] = acc[0] / acc[1];
}

extern "C" void kernel_launch(void* const* d_in, const int* in_sizes, int n_in,
                              void* d_out, int out_size, void* d_ws, size_t ws_size,
                              hipStream_t stream) {
  const float* preds = (const float*)d_in[0];
  const int* gt = (const int*)d_in[1];
  float* out = (float*)d_out;
  float* acc = (float*)d_ws;          // 2 floats of scratch
  const int total = in_sizes[0];      // 128*4096*50

  hipMemsetAsync(acc, 0, 2 * sizeof(float), stream);  // ws is re-poisoned 0xAA every call

  const int threads = 256;
  const int blocks = 4096;            // ~6.25 float4 iters/thread, 16 blocks/CU
  pitch_loss_main<<<blocks, threads, 0, stream>>>(preds, gt, acc, total);
  pitch_loss_finalize<<<1, 1, 0, stream>>>(acc, out);
}

// Round 2
// 231.039 us; speedup vs baseline: 1.0404x; 1.0404x over previous
//
#include <hip/hip_runtime.h>

#define NBINS 50
#define PAD_G 100

// Gaussian kernel (5 taps, sigma=0.5), normalized: K0=e^-8/S, K1=e^-2/S, K2=1/S
#define K0 2.6387004e-4f
#define K1 1.0645079e-1f
#define K2 7.8657085e-1f

__device__ __forceinline__ int quant(int g) {
  // exact floor((g-50)/6) clipped to [0,49]; g in [0,200)
  int d = g - 50;
  d = (d < 0) ? 0 : d;
  int q = __umul24((unsigned)d, 10923u) >> 16;  // exact /6 for d <= ~32000
  return (q > NBINS - 1) ? (NBINS - 1) : q;
}

__device__ __forceinline__ float softplus_stable(float x) {
  // max(x,0) + log1p(exp(-|x|)); neg/abs fold into VOP3 modifiers
  return fmaxf(x, 0.f) + __logf(1.f + __expf(-fabsf(x)));
}

__global__ __launch_bounds__(256) void pitch_loss_fused(
    const float4* __restrict__ preds4,
    const int* __restrict__ gt,
    int nvec, int total, int nframes,
    float* __restrict__ acc,      // [0]=num(float) [1]=den(uint) [2]=ctr(uint)
    float* __restrict__ out)
{
  // t(q, dj) with j = q-2+dj; all blur mass has |j-q|<=2 (incl. reflection)
  __shared__ float s_tab[NBINS * 5];
  if (threadIdx.x < NBINS * 5) {
    const int idx = threadIdx.x;
    const int q = idx / 5;
    const int dj = idx - q * 5;
    const int j = q - 2 + dj;
    float t = 0.f;
    if (0 <= j && j < NBINS) {
      const float kk[5] = {K0, K1, K2, K1, K0};
#pragma unroll
      for (int i = 0; i < 5; ++i) {
        int m = j - 2 + i;                       // reference: ohp[j+i] = oh[refl(j+i-2)]
        m = (m < 0) ? -m : m;
        m = (m > NBINS - 1) ? 2 * (NBINS - 1) - m : m;
        if (m == q) t += kk[i];
      }
    }
    s_tab[idx] = t;
  }
  __syncthreads();

  float num = 0.f;
  unsigned cnt = 0;
  const int stride = gridDim.x * blockDim.x;
  const int tid0 = blockIdx.x * blockDim.x + threadIdx.x;

  for (int v = tid0; v < nvec; v += stride) {
    const float4 p4 = preds4[v];
    const int e0 = v << 2;
    const int f0 = (int)((unsigned)e0 / 50u);    // compiler magic-mul
    const int j0 = e0 - f0 * 50;
    int f1 = f0 + 1; f1 = (f1 >= nframes) ? nframes - 1 : f1;
    const int g0 = gt[f0];
    const int g1 = gt[f1];
    const int q0 = quant(g0);
    const int q1 = quant(g1);
    const float p[4] = {p4.x, p4.y, p4.z, p4.w};
#pragma unroll
    for (int u = 0; u < 4; ++u) {
      int j = j0 + u;
      const bool wrap = (j >= NBINS);
      const int g = wrap ? g1 : g0;
      const int q = wrap ? q1 : q0;
      j = wrap ? j - NBINS : j;
      const float x = p[u];
      const float sp = softplus_stable(x);
      const int dj = j - q + 2;
      const int djc = min(max(dj, 0), 4);
      float t = s_tab[q * 5 + djc];              // always-execute LDS read
      t = ((unsigned)dj < 5u) ? t : 0.f;
      const bool valid = (g != PAD_G);
      num += valid ? (sp - x * t) : 0.f;
      cnt += valid ? 1u : 0u;
    }
  }

  // scalar tail (empty for 26214400, kept for generality)
  for (int e = (nvec << 2) + tid0; e < total; e += stride) {
    const int f = (int)((unsigned)e / 50u);
    const int j = e - f * 50;
    const int g = gt[f];
    if (g != PAD_G) {
      const int q = quant(g);
      const int dj = j - q + 2;
      const int djc = min(max(dj, 0), 4);
      float t = s_tab[q * 5 + djc];
      t = ((unsigned)dj < 5u) ? t : 0.f;
      const float x = ((const float*)preds4)[e];
      num += softplus_stable(x) - x * t;
      cnt += 1u;
    }
  }

  // wave-64 shuffle reduction
#pragma unroll
  for (int off = 32; off > 0; off >>= 1) {
    num += __shfl_down(num, off, 64);
    cnt += __shfl_down(cnt, off, 64);
  }
  __shared__ float sn[4];
  __shared__ unsigned sc[4];
  const int wv = threadIdx.x >> 6;
  if ((threadIdx.x & 63) == 0) { sn[wv] = num; sc[wv] = cnt; }
  __syncthreads();
  if (threadIdx.x == 0) {
    const float n = sn[0] + sn[1] + sn[2] + sn[3];
    const unsigned c = sc[0] + sc[1] + sc[2] + sc[3];
    atomicAdd(&acc[0], n);
    atomicAdd((unsigned*)&acc[1], c);
    __threadfence();
    const unsigned done = atomicAdd((unsigned*)&acc[2], 1u);
    if (done == gridDim.x - 1) {                 // last block finalizes
      const float tn = atomicAdd(&acc[0], 0.f);          // coherent read
      const unsigned tc = atomicAdd((unsigned*)&acc[1], 0u);
      out[0] = tn / (float)tc;
    }
  }
}

extern "C" void kernel_launch(void* const* d_in, const int* in_sizes, int n_in,
                              void* d_out, int out_size, void* d_ws, size_t ws_size,
                              hipStream_t stream) {
  const float4* preds4 = (const float4*)d_in[0];
  const int* gt = (const int*)d_in[1];
  float* out = (float*)d_out;
  float* acc = (float*)d_ws;
  const int total = in_sizes[0];     // 128*4096*50 = 26214400
  const int nframes = in_sizes[1];   // 524288
  const int nvec = total >> 2;

  hipMemsetAsync(acc, 0, 3 * sizeof(float), stream);  // num, den, ctr

  const int threads = 256;
  const int blocks = 2048;           // 8 blocks/CU, 12.5 float4/thread
  pitch_loss_fused<<<blocks, threads, 0, stream>>>(preds4, gt, nvec, total,
                                                   nframes, acc, out);
}